// Round 11
// baseline (398.343 us; speedup 1.0000x reference)
//
#include <hip/hip_runtime.h>
#include <hip/hip_bf16.h>

// ClusterMemory forward: loss = mean_i [ logsumexp_j( <x_i, f_j>/T ) - <x_i, f_{t_i}>/T ]
// x_i = inputs_i / max(||inputs_i||, 1e-12),  T = 0.05,  B=4096, N=131072, D=256.
//
// R11: 256x256 block tile (m201-class). 8 waves 2wrx4wc, wave out 128x64,
// acc[8][4] (128 VGPR), launch_bounds(512,1) for the 256-VGPR band.
// A and B both staged via global_load_lds(16B, inverse-swizzled source) into
// dbuf-2 LDS (4x32KB = 128KB dynamic). Per kt: [vmcnt(0); barrier] at head
// (sole barrier), then 4 quadrant phases {ds_read subtile; stage; MFMA x16},
// stages front-loaded in phases 1-2. Max-free base-2 LSE epilogue per nt
// (native v_exp_f32). XCD-aligned block swizzle.

typedef __attribute__((ext_vector_type(8))) short bf16x8;
typedef __attribute__((ext_vector_type(4))) float f32x4;
typedef __attribute__((address_space(1))) unsigned int u32g;
typedef __attribute__((address_space(3))) unsigned int u32l;

#define B_ROWS   4096
#define N_FEATS  131072
#define D_DIM    256
// (1/0.05) * log2(e)
#define SCALE_B2 28.853900817779268f
#define LN2F     0.69314718055994531f

#define BM 256
#define BN 256
#define BKT 64
#define NCHUNK 16                       // grid y
#define COLS_PB (N_FEATS / NCHUNK)      // 8192 cols per block
#define NTILES  (COLS_PB / BN)          // 32 column tiles per block
#define TT      (NTILES * 4)            // 128 kt-tiles per block
#define HBUF    16384                   // half-tile bytes (128 rows x 128B)
#define BUFSZ   32768                   // one kt tile (A or B)
#define NSLICE  (NCHUNK * 4)            // 64 partial slices per row

#define E2(x) __builtin_amdgcn_exp2f(x)

static __device__ __forceinline__ unsigned short f2bf(float x) {
    __hip_bfloat16 h = __float2bfloat16(x);
    return __builtin_bit_cast(unsigned short, h);
}
static __device__ __forceinline__ float bf2f(unsigned short u) {
    return __builtin_bit_cast(float, ((unsigned int)u) << 16);
}

// ---------------- kernel 1: row-normalize + scale + cvt to bf16 ----------------
__global__ __launch_bounds__(64) void k_normalize(const float* __restrict__ in,
                                                  unsigned short* __restrict__ xb) {
    const int row  = blockIdx.x;
    const int lane = threadIdx.x;
    float4 v = *(const float4*)(in + (size_t)row * D_DIM + lane * 4);
    float ss = v.x * v.x + v.y * v.y + v.z * v.z + v.w * v.w;
#pragma unroll
    for (int mask = 1; mask < 64; mask <<= 1) ss += __shfl_xor(ss, mask);
    const float sc = SCALE_B2 / fmaxf(sqrtf(ss), 1e-12f);
    ushort4 o;
    o.x = f2bf(v.x * sc); o.y = f2bf(v.y * sc);
    o.z = f2bf(v.z * sc); o.w = f2bf(v.w * sc);
    *(ushort4*)(xb + (size_t)row * D_DIM + lane * 4) = o;
}

// ---------------- kernel 2: features fp32 -> bf16 ----------------
__global__ __launch_bounds__(256) void k_cvt_feats(const float* __restrict__ f,
                                                   unsigned short* __restrict__ fb) {
    const int total4 = N_FEATS * D_DIM / 4;
    const int stride = gridDim.x * blockDim.x;
    for (int i = blockIdx.x * blockDim.x + threadIdx.x; i < total4; i += stride) {
        float4 v = ((const float4*)f)[i];
        ushort4 o;
        o.x = f2bf(v.x); o.y = f2bf(v.y); o.z = f2bf(v.z); o.w = f2bf(v.w);
        ((ushort4*)fb)[i] = o;
    }
}

#define GL(src_, dst_) __builtin_amdgcn_global_load_lds((const u32g*)(src_), (u32l*)(dst_), 16, 0, 0)

// stage half h_ of kt-tile Tn_ into parity P_ buffer (A from xb, B from fb)
#define STG_A(Tn_, P_, h_) do { if ((Tn_) < TT) {                                     \
        const unsigned short* s_ = xb + (size_t)(brow + (h_) * 128) * D_DIM + ((Tn_) & 3) * BKT; \
        char* d_ = As + (P_) * BUFSZ + (h_) * HBUF + dBase;                           \
        GL(s_ + E0v, d_); GL(s_ + E1v, d_ + 8192); } } while (0)
#define STG_B(Tn_, P_, h_) do { if ((Tn_) < TT) {                                     \
        const unsigned short* s_ = fb + (nbase + (size_t)((Tn_) >> 2) * BN + (h_) * 128) * D_DIM + ((Tn_) & 3) * BKT; \
        char* d_ = Bsm + (P_) * BUFSZ + (h_) * HBUF + dBase;                          \
        GL(s_ + E0v, d_); GL(s_ + E1v, d_ + 8192); } } while (0)

// ds-read register subtiles (literal parity / half indices)
#define RD_A(P_, mh_) do {                                                            \
        const char* ab_ = As + (P_) * BUFSZ + (mh_) * 8192;                           \
        _Pragma("unroll")                                                             \
        for (int mf = 0; mf < 4; ++mf)                                                \
        _Pragma("unroll")                                                             \
            for (int ks2 = 0; ks2 < 2; ++ks2)                                         \
                afr[mf][ks2] = *(const bf16x8*)(ab_ + aOff[mf][ks2]);                 \
    } while (0)
#define RD_B(P_, nh_) do {                                                            \
        const char* bb_ = Bsm + (P_) * BUFSZ + (nh_) * 4096;                          \
        _Pragma("unroll")                                                             \
        for (int nf = 0; nf < 2; ++nf)                                                \
        _Pragma("unroll")                                                             \
            for (int ks2 = 0; ks2 < 2; ++ks2)                                         \
                bfr[nf][ks2] = *(const bf16x8*)(bb_ + bOff[nf][ks2]);                 \
    } while (0)

// 16 MFMA quadrant; ZC_ replaces acc reset on the first K-slice of a tile row
#define MM(mh_, nh_, ZC_) do {                                                        \
        __builtin_amdgcn_s_setprio(1);                                                \
        _Pragma("unroll")                                                             \
        for (int ks2 = 0; ks2 < 2; ++ks2)                                             \
        _Pragma("unroll")                                                             \
            for (int mf = 0; mf < 4; ++mf)                                            \
        _Pragma("unroll")                                                             \
                for (int nf = 0; nf < 2; ++nf) {                                      \
                    const f32x4 cin_ = ((ZC_) && ks2 == 0) ? (f32x4){0.f, 0.f, 0.f, 0.f} \
                                                           : acc[(mh_) * 4 + mf][(nh_) * 2 + nf]; \
                    acc[(mh_) * 4 + mf][(nh_) * 2 + nf] =                             \
                        __builtin_amdgcn_mfma_f32_16x16x32_bf16(                      \
                            afr[mf][ks2], bfr[nf][ks2], cin_, 0, 0, 0);               \
                }                                                                     \
        __builtin_amdgcn_s_setprio(0);                                                \
    } while (0)

// one kt: head barrier (sole sync), 4 quadrant phases, stages front-loaded
#define KT(ktL, ZCL, t4_) do {                                                        \
        asm volatile("s_waitcnt vmcnt(0)\ns_barrier" ::: "memory");                   \
        RD_A((ktL) & 1, 0); RD_B((ktL) & 1, 0);                                       \
        STG_A((t4_) + (ktL) + 1, ((ktL) + 1) & 1, 0);                                 \
        STG_A((t4_) + (ktL) + 1, ((ktL) + 1) & 1, 1);                                 \
        MM(0, 0, ZCL);                                                                \
        RD_B((ktL) & 1, 1);                                                           \
        STG_B((t4_) + (ktL) + 1, ((ktL) + 1) & 1, 0);                                 \
        STG_B((t4_) + (ktL) + 1, ((ktL) + 1) & 1, 1);                                 \
        MM(0, 1, ZCL);                                                                \
        RD_A((ktL) & 1, 1); RD_B((ktL) & 1, 0); MM(1, 0, ZCL);                        \
        RD_B((ktL) & 1, 1); MM(1, 1, ZCL);                                            \
    } while (0)

// per-nt exp2-accumulate (max-free; |logit_b2| <= 28.9, sum < fp32 max)
#define EPI() do {                                                                    \
        _Pragma("unroll")                                                             \
        for (int m = 0; m < 8; ++m)                                                   \
        _Pragma("unroll")                                                             \
            for (int j = 0; j < 4; ++j)                                               \
                s_run[m * 4 + j] += (E2(acc[m][0][j]) + E2(acc[m][1][j]))             \
                                  + (E2(acc[m][2][j]) + E2(acc[m][3][j]));            \
    } while (0)

// ---------------- kernel 3: fused GEMM + max-free base-2 LSE ----------------
// grid = (16 m-blocks, 16 n-chunks) = 256 blocks (1/CU), block = 512 (8 waves: 2wr x 4wc)
template <bool BF16B>
__global__ __launch_bounds__(512, 1) void k_lse_gemm(
    const unsigned short* __restrict__ xb,
    const float* __restrict__ featf,
    const unsigned short* __restrict__ fb,
    float* __restrict__ partials)
{
    extern __shared__ char smem[];
    char* As  = smem;            // 2 x 32KB
    char* Bsm = smem + 65536;    // 2 x 32KB

    // XCD-aligned bijective swizzle: 256 blocks, 2 n-chunks per XCD
    const int hw  = blockIdx.y * 16 + blockIdx.x;
    const int lid = (hw & 7) * 32 + (hw >> 3);
    const int bx  = lid & 15;         // m-block  0..15
    const int by  = lid >> 4;         // n-chunk  0..15

    const int tid  = threadIdx.x;
    const int lane = tid & 63;
    const int w    = tid >> 6;
    const int wr   = w >> 2;          // 0..1 : 128-row slice
    const int wc   = w & 3;           // 0..3 : 64-col slice
    const int l15  = lane & 15;
    const int l4q  = lane >> 4;       // 0..3

    const int brow     = bx * BM;
    const size_t nbase = (size_t)by * COLS_PB;

    // swizzled ds_read byte offsets (loop-invariant)
    const int swz = (l15 & 7) << 4;
    int aOff[4][2], bOff[2][2];
#pragma unroll
    for (int mf = 0; mf < 4; ++mf)
#pragma unroll
        for (int ks2 = 0; ks2 < 2; ++ks2)
            aOff[mf][ks2] = (wr * 128 + mf * 16 + l15) * 128 + ((ks2 * 64 + l4q * 16) ^ swz);
#pragma unroll
    for (int nf = 0; nf < 2; ++nf)
#pragma unroll
        for (int ks2 = 0; ks2 < 2; ++ks2)
            bOff[nf][ks2] = (wc * 64 + nf * 16 + l15) * 128 + ((ks2 * 64 + l4q * 16) ^ swz);

    // inverse-swizzled staging source element offsets + LDS dest base
    int E0v, E1v;
    {
        const int p0 = w * 1024 + lane * 16;
        const int c0 = p0 >> 7;
        E0v = c0 * D_DIM + ((((p0 ^ ((c0 & 7) << 4)) >> 4) & 7) * 8);
        const int p1 = p0 + 8192;
        const int c1 = p1 >> 7;
        E1v = c1 * D_DIM + ((((p1 ^ ((c1 & 7) << 4)) >> 4) & 7) * 8);
    }
    const int dBase = w * 1024;

    bf16x8 afr[4][2];
    bf16x8 bfr[2][2];
    f32x4 acc[8][4];
    float s_run[32];
#pragma unroll
    for (int r = 0; r < 32; ++r) s_run[r] = 0.f;

    if (BF16B) {
        // prologue: stage kt-tile 0 (parity 0)
        STG_A(0, 0, 0); STG_A(0, 0, 1); STG_B(0, 0, 0); STG_B(0, 0, 1);
        for (int nt = 0; nt < NTILES; ++nt) {
            const int t4 = nt * 4;
            KT(0, true,  t4);
            KT(1, false, t4);
            KT(2, false, t4);
            KT(3, false, t4);
            EPI();
        }
    } else {
        // fp32 fallback: single-buffer, syncthreads discipline (correctness path)
        for (int nt = 0; nt < NTILES; ++nt) {
            for (int kt = 0; kt < 4; ++kt) {
                __syncthreads();
#pragma unroll
                for (int c = 0; c < 4; ++c) {
                    const int q   = (tid + c * 512) * 16;       // [0, 32768)
                    const int row = q >> 7;
                    const int dst = q ^ ((row & 7) << 4);
                    const int kel = (q & 127) >> 1;
                    int4 va = *(const int4*)(xb + (size_t)(brow + row) * D_DIM + kt * BKT + kel);
                    *(int4*)(As + dst) = va;
                    const float* sb = featf + (nbase + (size_t)nt * BN + row) * D_DIM + kt * BKT + kel;
                    float4 f0 = *(const float4*)sb, f1 = *(const float4*)(sb + 4);
                    unsigned short ub[8] = {f2bf(f0.x), f2bf(f0.y), f2bf(f0.z), f2bf(f0.w),
                                            f2bf(f1.x), f2bf(f1.y), f2bf(f1.z), f2bf(f1.w)};
                    *(int4*)(Bsm + dst) = *(int4*)ub;
                }
                __syncthreads();
                const bool zc = (kt == 0);
                RD_A(0, 0); RD_B(0, 0); MM(0, 0, zc);
                RD_B(0, 1);             MM(0, 1, zc);
                RD_A(0, 1); RD_B(0, 0); MM(1, 0, zc);
                RD_B(0, 1);             MM(1, 1, zc);
            }
            EPI();
        }
    }

    // ---- cross-lane sum over the 16 column lanes ----
#pragma unroll
    for (int r = 0; r < 32; ++r) {
        float S = s_run[r];
#pragma unroll
        for (int mask = 1; mask < 16; mask <<= 1) S += __shfl_xor(S, mask);
        s_run[r] = S;
    }
    if (l15 == 0) {
        const int slice = by * 4 + wc;
#pragma unroll
        for (int r = 0; r < 32; ++r) {
            const int m = r >> 2, j = r & 3;
            const int row = brow + wr * 128 + m * 16 + l4q * 4 + j;
            partials[(size_t)row * NSLICE + slice] = s_run[r];
        }
    }
}

// ---------------- kernel 4: merge slices + target logit + per-row loss ----------------
__global__ __launch_bounds__(64) void k_finalize(const float* __restrict__ partials,
                                                 const unsigned short* __restrict__ xb,
                                                 const float* __restrict__ feats,
                                                 const int* __restrict__ targets,
                                                 float* __restrict__ loss) {
    const int row  = blockIdx.x;
    const int lane = threadIdx.x;
    float S = partials[(size_t)row * NSLICE + lane];

    const int t = targets[row];
    ushort4 xv = *(const ushort4*)(xb + (size_t)row * D_DIM + lane * 4);
    float4  fv = *(const float4*)(feats + (size_t)t * D_DIM + lane * 4);
    float dot = bf2f(xv.x) * fv.x + bf2f(xv.y) * fv.y +
                bf2f(xv.z) * fv.z + bf2f(xv.w) * fv.w;   // base-2-scaled target logit
#pragma unroll
    for (int mask = 1; mask < 64; mask <<= 1) {
        S   += __shfl_xor(S, mask);
        dot += __shfl_xor(dot, mask);
    }
    if (lane == 0) loss[row] = LN2F * (__builtin_amdgcn_logf(S) - dot);
}

// ---------------- kernel 5: mean over rows ----------------
__global__ __launch_bounds__(256) void k_reduce(const float* __restrict__ loss,
                                                float* __restrict__ out) {
    __shared__ float sm[4];
    const int tid = threadIdx.x;
    float s = 0.f;
    for (int i = tid; i < B_ROWS; i += 256) s += loss[i];
#pragma unroll
    for (int mask = 1; mask < 64; mask <<= 1) s += __shfl_xor(s, mask);
    if ((tid & 63) == 0) sm[tid >> 6] = s;
    __syncthreads();
    if (tid == 0) out[0] = (sm[0] + sm[1] + sm[2] + sm[3]) * (1.0f / B_ROWS);
}

extern "C" void kernel_launch(void* const* d_in, const int* in_sizes, int n_in,
                              void* d_out, int out_size, void* d_ws, size_t ws_size,
                              hipStream_t stream) {
    const float* inputs  = (const float*)d_in[0];
    const int*   targets = (const int*)d_in[1];
    const float* feats   = (const float*)d_in[4];
    float* out = (float*)d_out;

    char* ws = (char*)d_ws;
    const size_t off_xb       = 0;                                            // 2 MB
    const size_t off_partials = off_xb + (size_t)B_ROWS * D_DIM * 2;
    const size_t off_loss     = off_partials + (size_t)B_ROWS * NSLICE * sizeof(float);
    const size_t off_fb       = off_loss + (size_t)B_ROWS * sizeof(float);
    const size_t need_fb      = off_fb + (size_t)N_FEATS * D_DIM * 2;         // +64 MB

    unsigned short* xb = (unsigned short*)(ws + off_xb);
    float* partials    = (float*)(ws + off_partials);
    float* loss        = (float*)(ws + off_loss);
    unsigned short* fb = (unsigned short*)(ws + off_fb);
    const bool precvt  = ws_size >= need_fb;

    static bool attrib_set = false;   // host-side idempotent attribute (not device state)
    if (!attrib_set) {
        hipFuncSetAttribute((const void*)&k_lse_gemm<true>,
                            hipFuncAttributeMaxDynamicSharedMemorySize, 131072);
        hipFuncSetAttribute((const void*)&k_lse_gemm<false>,
                            hipFuncAttributeMaxDynamicSharedMemorySize, 131072);
        attrib_set = true;
    }

    k_normalize<<<B_ROWS, 64, 0, stream>>>(inputs, xb);
    if (precvt) {
        k_cvt_feats<<<2048, 256, 0, stream>>>(feats, fb);
        k_lse_gemm<true><<<dim3(16, NCHUNK), 512, 131072, stream>>>(xb, feats, fb, partials);
    } else {
        k_lse_gemm<false><<<dim3(16, NCHUNK), 512, 131072, stream>>>(xb, feats, fb, partials);
    }
    k_finalize<<<B_ROWS, 64, 0, stream>>>(partials, xb, feats, targets, loss);
    k_reduce<<<1, 256, 0, stream>>>(loss, out);
}

// Round 13
// 365.716 us; speedup vs baseline: 1.0892x; 1.0892x over previous
//
#include <hip/hip_runtime.h>
#include <hip/hip_bf16.h>

// ClusterMemory forward: loss = mean_i [ logsumexp_j( <x_i, f_j>/T ) - <x_i, f_{t_i}>/T ]
// x_i = inputs_i / max(||inputs_i||, 1e-12),  T = 0.05,  B=4096, N=131072, D=256.
//
// R13 = R12 with the KT parity bug fixed (KT takes a PARITY literal 0/1;
// R12 passed 0..3 and read B's LDS as A -> NaN). 256x256 tile, register-dieted:
// acc[8][4]=128 regs; s_own[2] + per-nt butterfly reduce; bfr[2][2]; ds
// addresses as base regs + literal imms. A+B dbuf-2 128KB dynamic LDS,
// global_load_lds(16B) inverse-swizzled source, one vmcnt(0)+barrier per kt,
// EPI deferred past barrier+stage, setprio around MFMA, XCD-aligned swizzle.

typedef __attribute__((ext_vector_type(8))) short bf16x8;
typedef __attribute__((ext_vector_type(4))) float f32x4;
typedef __attribute__((address_space(1))) unsigned int u32g;
typedef __attribute__((address_space(3))) unsigned int u32l;

#define B_ROWS   4096
#define N_FEATS  131072
#define D_DIM    256
// (1/0.05) * log2(e)
#define SCALE_B2 28.853900817779268f
#define LN2F     0.69314718055994531f

#define BM 256
#define BN 256
#define BKT 64
#define NCHUNK 16                       // grid y
#define COLS_PB (N_FEATS / NCHUNK)      // 8192 cols per block
#define NTILES  (COLS_PB / BN)          // 32 column tiles per block
#define HBUF    16384                   // half-tile bytes (128 rows x 128B)
#define BUFSZ   32768                   // one kt tile (A or B)
#define NSLICE  (NCHUNK * 4)            // 64 partial slices per row

#define E2(x) __builtin_amdgcn_exp2f(x)

static __device__ __forceinline__ unsigned short f2bf(float x) {
    __hip_bfloat16 h = __float2bfloat16(x);
    return __builtin_bit_cast(unsigned short, h);
}
static __device__ __forceinline__ float bf2f(unsigned short u) {
    return __builtin_bit_cast(float, ((unsigned int)u) << 16);
}

// ---------------- kernel 1: row-normalize + scale + cvt to bf16 ----------------
__global__ __launch_bounds__(64) void k_normalize(const float* __restrict__ in,
                                                  unsigned short* __restrict__ xb) {
    const int row  = blockIdx.x;
    const int lane = threadIdx.x;
    float4 v = *(const float4*)(in + (size_t)row * D_DIM + lane * 4);
    float ss = v.x * v.x + v.y * v.y + v.z * v.z + v.w * v.w;
#pragma unroll
    for (int mask = 1; mask < 64; mask <<= 1) ss += __shfl_xor(ss, mask);
    const float sc = SCALE_B2 / fmaxf(sqrtf(ss), 1e-12f);
    ushort4 o;
    o.x = f2bf(v.x * sc); o.y = f2bf(v.y * sc);
    o.z = f2bf(v.z * sc); o.w = f2bf(v.w * sc);
    *(ushort4*)(xb + (size_t)row * D_DIM + lane * 4) = o;
}

// ---------------- kernel 2: features fp32 -> bf16 ----------------
__global__ __launch_bounds__(256) void k_cvt_feats(const float* __restrict__ f,
                                                   unsigned short* __restrict__ fb) {
    const int total4 = N_FEATS * D_DIM / 4;
    const int stride = gridDim.x * blockDim.x;
    for (int i = blockIdx.x * blockDim.x + threadIdx.x; i < total4; i += stride) {
        float4 v = ((const float4*)f)[i];
        ushort4 o;
        o.x = f2bf(v.x); o.y = f2bf(v.y); o.z = f2bf(v.z); o.w = f2bf(v.w);
        ((ushort4*)fb)[i] = o;
    }
}

#define GL(src_, dst_) __builtin_amdgcn_global_load_lds((const u32g*)(src_), (u32l*)(dst_), 16, 0, 0)

// stage kt-tile t_ (A from xb rows, B from fb rows) into parity P_ (literal)
#define STG(t_, P_) do {                                                              \
        const int nt_ = (t_) >> 2, kt_ = (t_) & 3;                                    \
        const unsigned short* sa0_ = xb + (size_t)brow * D_DIM + kt_ * BKT;           \
        const unsigned short* sa1_ = sa0_ + (size_t)128 * D_DIM;                      \
        const unsigned short* sb0_ = fb + (nbase + (size_t)nt_ * BN) * D_DIM + kt_ * BKT; \
        const unsigned short* sb1_ = sb0_ + (size_t)128 * D_DIM;                      \
        char* da_ = As  + (P_) * BUFSZ + dBase;                                       \
        char* db_ = Bsm + (P_) * BUFSZ + dBase;                                       \
        GL(sa0_ + E0v, da_);         GL(sa0_ + E1v, da_ + 8192);                      \
        GL(sa1_ + E0v, da_ + HBUF);  GL(sa1_ + E1v, da_ + HBUF + 8192);               \
        GL(sb0_ + E0v, db_);         GL(sb0_ + E1v, db_ + 8192);                      \
        GL(sb1_ + E0v, db_ + HBUF);  GL(sb1_ + E1v, db_ + HBUF + 8192);               \
    } while (0)

// ds-read A m-half (8 x b128): afr[mf][ks2]
#define RD_A(PL, mh) do {                                                             \
        _Pragma("unroll")                                                             \
        for (int mf = 0; mf < 4; ++mf) {                                              \
            afr[mf][0] = *(const bf16x8*)(As + (PL) * BUFSZ + (mh) * 8192 + mf * 2048 + aA0); \
            afr[mf][1] = *(const bf16x8*)(As + (PL) * BUFSZ + (mh) * 8192 + mf * 2048 + aA1); \
        }                                                                             \
    } while (0)
// ds-read B n-half (4 x b128): bfr[nf][ks2]
#define RD_B(PL, nh) do {                                                             \
        _Pragma("unroll")                                                             \
        for (int nf = 0; nf < 2; ++nf) {                                              \
            bfr[nf][0] = *(const bf16x8*)(Bsm + (PL) * BUFSZ + (nh) * 4096 + nf * 2048 + bB0); \
            bfr[nf][1] = *(const bf16x8*)(Bsm + (PL) * BUFSZ + (nh) * 4096 + nf * 2048 + bB1); \
        }                                                                             \
    } while (0)

// 16-MFMA quadrant; ZC replaces acc reset on the first K-slice of a tile row
#define MM(mh, nh, ZC_) do {                                                          \
        __builtin_amdgcn_s_setprio(1);                                                \
        _Pragma("unroll")                                                             \
        for (int ks2 = 0; ks2 < 2; ++ks2)                                             \
        _Pragma("unroll")                                                             \
            for (int mf = 0; mf < 4; ++mf)                                            \
        _Pragma("unroll")                                                             \
                for (int nf = 0; nf < 2; ++nf) {                                      \
                    const f32x4 cin_ = ((ZC_) && ks2 == 0) ? (f32x4){0.f, 0.f, 0.f, 0.f} \
                                                           : acc[(mh) * 4 + mf][(nh) * 2 + nf]; \
                    acc[(mh) * 4 + mf][(nh) * 2 + nf] =                               \
                        __builtin_amdgcn_mfma_f32_16x16x32_bf16(                      \
                            afr[mf][ks2], bfr[nf][ks2], cin_, 0, 0, 0);               \
                }                                                                     \
        __builtin_amdgcn_s_setprio(0);                                                \
    } while (0)

// one kt-tile's 4 quadrants; PL is the PARITY literal (0/1)
#define KT(PL, ZCL) do {                                                              \
        RD_A(PL, 0); RD_B(PL, 0); MM(0, 0, ZCL);                                      \
        RD_B(PL, 1); MM(0, 1, ZCL);                                                   \
        RD_A(PL, 1); RD_B(PL, 0); MM(1, 0, ZCL);                                      \
        RD_B(PL, 1); MM(1, 1, ZCL);                                                   \
    } while (0)

#define BAR() asm volatile("s_waitcnt vmcnt(0)\ns_barrier" ::: "memory")

// per-nt: exp2, 16-lane butterfly row-reduce, accumulate into 2 owned slots
#define EPI() do {                                                                    \
        _Pragma("unroll")                                                             \
        for (int m = 0; m < 8; ++m)                                                   \
        _Pragma("unroll")                                                             \
            for (int j = 0; j < 4; ++j) {                                             \
                float t_ = (E2(acc[m][0][j]) + E2(acc[m][1][j]))                      \
                         + (E2(acc[m][2][j]) + E2(acc[m][3][j]));                     \
                t_ += __shfl_xor(t_, 1); t_ += __shfl_xor(t_, 2);                     \
                t_ += __shfl_xor(t_, 4); t_ += __shfl_xor(t_, 8);                     \
                const int r_ = m * 4 + j;                                             \
                s_own[r_ & 1] += (l15 == (r_ >> 1)) ? t_ : 0.0f;                      \
            }                                                                         \
    } while (0)

// ---------------- kernel 3: fused GEMM + max-free base-2 LSE ----------------
// grid = (16 m-blocks, 16 n-chunks) = 256 blocks (1/CU), block = 512 (8 waves: 2wr x 4wc)
template <bool BF16B>
__global__ __launch_bounds__(512, 1) void k_lse_gemm(
    const unsigned short* __restrict__ xb,
    const float* __restrict__ featf,
    const unsigned short* __restrict__ fb,
    float* __restrict__ partials)
{
    extern __shared__ char smem[];
    char* As  = smem;            // 2 x 32KB
    char* Bsm = smem + 65536;    // 2 x 32KB

    // XCD-aligned bijective swizzle (256 blocks % 8 == 0)
    const int hw  = blockIdx.y * 16 + blockIdx.x;
    const int lid = (hw & 7) * 32 + (hw >> 3);
    const int bx  = lid & 15;         // m-block  0..15
    const int by  = lid >> 4;         // n-chunk  0..15

    const int tid  = threadIdx.x;
    const int lane = tid & 63;
    const int w    = tid >> 6;
    const int wr   = w >> 2;          // 0..1 : 128-row slice
    const int wc   = w & 3;           // 0..3 : 64-col slice
    const int l15  = lane & 15;
    const int l4q  = lane >> 4;       // 0..3

    const int brow     = bx * BM;
    const size_t nbase = (size_t)by * COLS_PB;

    // swizzled ds_read k-offsets: koff(ks2) = ((l4q^(s&3))<<4) | ((ks2^(s>>2))<<6)
    const int s_   = l15 & 7;
    const int kf0  = ((l4q ^ (s_ & 3)) << 4) | (((s_ >> 2) & 1) << 6);
    const int kf1  = kf0 ^ 64;
    const int aA0  = wr * 16384 + l15 * 128 + kf0;
    const int aA1  = wr * 16384 + l15 * 128 + kf1;
    const int bB0  = wc * 8192 + l15 * 128 + kf0;
    const int bB1  = wc * 8192 + l15 * 128 + kf1;

    // inverse-swizzled staging source element offsets + LDS dest base
    int E0v, E1v;
    {
        const int p0 = w * 1024 + lane * 16;
        const int c0 = p0 >> 7;
        E0v = c0 * D_DIM + ((((p0 ^ ((c0 & 7) << 4)) >> 4) & 7) * 8);
        const int p1 = p0 + 8192;
        const int c1 = p1 >> 7;
        E1v = c1 * D_DIM + ((((p1 ^ ((c1 & 7) << 4)) >> 4) & 7) * 8);
    }
    const int dBase = w * 1024;

    bf16x8 afr[4][2];
    bf16x8 bfr[2][2];
    f32x4 acc[8][4];
    float s_own[2] = {0.f, 0.f};

    if (BF16B) {
        STG(0, 0);   // prologue: tile 0 -> parity 0
        // ---- nt = 0 (no EPI) ----
        BAR(); STG(1, 1); KT(0, true);
        BAR(); STG(2, 0); KT(1, false);
        BAR(); STG(3, 1); KT(0, false);
        BAR(); STG(4, 0); KT(1, false);
        // ---- nt = 1 .. NTILES-2 ----
        for (int nt = 1; nt < NTILES - 1; ++nt) {
            const int t0 = nt * 4;
            BAR(); STG(t0 + 1, 1); EPI(); KT(0, true);
            BAR(); STG(t0 + 2, 0); KT(1, false);
            BAR(); STG(t0 + 3, 1); KT(0, false);
            BAR(); STG(t0 + 4, 0); KT(1, false);
        }
        // ---- nt = NTILES-1 (no staging at kt3) ----
        {
            const int t0 = (NTILES - 1) * 4;
            BAR(); STG(t0 + 1, 1); EPI(); KT(0, true);
            BAR(); STG(t0 + 2, 0); KT(1, false);
            BAR(); STG(t0 + 3, 1); KT(0, false);
            BAR(); KT(1, false);
        }
        EPI();
    } else {
        // fp32 fallback: single-buffer, syncthreads discipline (correctness path)
        for (int nt = 0; nt < NTILES; ++nt) {
            for (int kt = 0; kt < 4; ++kt) {
                __syncthreads();
#pragma unroll
                for (int c = 0; c < 4; ++c) {
                    const int q   = (tid + c * 512) * 16;       // [0, 32768)
                    const int row = q >> 7;
                    const int dst = q ^ ((row & 7) << 4);
                    const int kel = (q & 127) >> 1;
                    int4 va = *(const int4*)(xb + (size_t)(brow + row) * D_DIM + kt * BKT + kel);
                    *(int4*)(As + dst) = va;
                    const float* sb = featf + (nbase + (size_t)nt * BN + row) * D_DIM + kt * BKT + kel;
                    float4 f0 = *(const float4*)sb, f1 = *(const float4*)(sb + 4);
                    unsigned short ub[8] = {f2bf(f0.x), f2bf(f0.y), f2bf(f0.z), f2bf(f0.w),
                                            f2bf(f1.x), f2bf(f1.y), f2bf(f1.z), f2bf(f1.w)};
                    *(int4*)(Bsm + dst) = *(int4*)ub;
                }
                __syncthreads();
                const bool zc = (kt == 0);
                KT(0, zc);
            }
            EPI();
        }
    }

    // ---- owner lanes write their 2 rows (all 64 lanes are owners) ----
    {
        const int slice = by * 4 + wc;
#pragma unroll
        for (int sl = 0; sl < 2; ++sl) {
            const int r   = l15 * 2 + sl;
            const int row = brow + wr * 128 + (r >> 2) * 16 + l4q * 4 + (r & 3);
            partials[(size_t)row * NSLICE + slice] = s_own[sl];
        }
    }
}

// ---------------- kernel 4: merge slices + target logit + per-row loss ----------------
__global__ __launch_bounds__(64) void k_finalize(const float* __restrict__ partials,
                                                 const unsigned short* __restrict__ xb,
                                                 const float* __restrict__ feats,
                                                 const int* __restrict__ targets,
                                                 float* __restrict__ loss) {
    const int row  = blockIdx.x;
    const int lane = threadIdx.x;
    float S = partials[(size_t)row * NSLICE + lane];

    const int t = targets[row];
    ushort4 xv = *(const ushort4*)(xb + (size_t)row * D_DIM + lane * 4);
    float4  fv = *(const float4*)(feats + (size_t)t * D_DIM + lane * 4);
    float dot = bf2f(xv.x) * fv.x + bf2f(xv.y) * fv.y +
                bf2f(xv.z) * fv.z + bf2f(xv.w) * fv.w;   // base-2-scaled target logit
#pragma unroll
    for (int mask = 1; mask < 64; mask <<= 1) {
        S   += __shfl_xor(S, mask);
        dot += __shfl_xor(dot, mask);
    }
    if (lane == 0) loss[row] = LN2F * (__builtin_amdgcn_logf(S) - dot);
}

// ---------------- kernel 5: mean over rows ----------------
__global__ __launch_bounds__(256) void k_reduce(const float* __restrict__ loss,
                                                float* __restrict__ out) {
    __shared__ float sm[4];
    const int tid = threadIdx.x;
    float s = 0.f;
    for (int i = tid; i < B_ROWS; i += 256) s += loss[i];
#pragma unroll
    for (int mask = 1; mask < 64; mask <<= 1) s += __shfl_xor(s, mask);
    if ((tid & 63) == 0) sm[tid >> 6] = s;
    __syncthreads();
    if (tid == 0) out[0] = (sm[0] + sm[1] + sm[2] + sm[3]) * (1.0f / B_ROWS);
}

extern "C" void kernel_launch(void* const* d_in, const int* in_sizes, int n_in,
                              void* d_out, int out_size, void* d_ws, size_t ws_size,
                              hipStream_t stream) {
    const float* inputs  = (const float*)d_in[0];
    const int*   targets = (const int*)d_in[1];
    const float* feats   = (const float*)d_in[4];
    float* out = (float*)d_out;

    char* ws = (char*)d_ws;
    const size_t off_xb       = 0;                                            // 2 MB
    const size_t off_partials = off_xb + (size_t)B_ROWS * D_DIM * 2;
    const size_t off_loss     = off_partials + (size_t)B_ROWS * NSLICE * sizeof(float);
    const size_t off_fb       = off_loss + (size_t)B_ROWS * sizeof(float);
    const size_t need_fb      = off_fb + (size_t)N_FEATS * D_DIM * 2;         // +64 MB

    unsigned short* xb = (unsigned short*)(ws + off_xb);
    float* partials    = (float*)(ws + off_partials);
    float* loss        = (float*)(ws + off_loss);
    unsigned short* fb = (unsigned short*)(ws + off_fb);
    const bool precvt  = ws_size >= need_fb;

    static bool attrib_set = false;   // host-side idempotent attribute (not device state)
    if (!attrib_set) {
        hipFuncSetAttribute((const void*)&k_lse_gemm<true>,
                            hipFuncAttributeMaxDynamicSharedMemorySize, 131072);
        hipFuncSetAttribute((const void*)&k_lse_gemm<false>,
                            hipFuncAttributeMaxDynamicSharedMemorySize, 131072);
        attrib_set = true;
    }

    k_normalize<<<B_ROWS, 64, 0, stream>>>(inputs, xb);
    if (precvt) {
        k_cvt_feats<<<2048, 256, 0, stream>>>(feats, fb);
        k_lse_gemm<true><<<dim3(16, NCHUNK), 512, 131072, stream>>>(xb, feats, fb, partials);
    } else {
        k_lse_gemm<false><<<dim3(16, NCHUNK), 512, 131072, stream>>>(xb, feats, fb, partials);
    }
    k_finalize<<<B_ROWS, 64, 0, stream>>>(partials, xb, feats, targets, loss);
    k_reduce<<<1, 256, 0, stream>>>(loss, out);
}